// Round 9
// baseline (344.116 us; speedup 1.0000x reference)
//
#include <hip/hip_runtime.h>
#include <hip/hip_bf16.h>

#define D_MODEL 256
#define NUM_HEADS 8
#define DIM_HEAD 32
#define SEQ 4096
#define BATCH 2
#define NROWS (BATCH * SEQ)              // 8192
#define LN_EPS 1e-6f
#define MASK_BIAS -1.0e9f
#define SCALE 0.17677669529663687f      // 1/sqrt(32)
#define LOG2E 1.4426950408889634f

typedef __attribute__((ext_vector_type(8))) short short8;   // 8 bf16 (4 VGPRs)
typedef __attribute__((ext_vector_type(4))) float f32x4;    // MFMA C/D

// fp32 -> bf16 bits (RNE)
static __device__ __forceinline__ unsigned short f2b(float f) {
    union { __hip_bfloat16 b; unsigned short u; } cv;
    cv.b = __float2bfloat16(f);
    return cv.u;
}
// packed fp32 pair -> bf16x2 (RNE), lo in low 16 bits
static __device__ __forceinline__ unsigned int pk_bf16(float lo, float hi) {
    union { __hip_bfloat162 v; unsigned int u; } cv;
    cv.v = __float22bfloat162_rn(make_float2(lo, hi));
    return cv.u;
}

// ---------------------------------------------------------------------------
// Kernel 1: fused QKV projection. x[8192,256] fp32 @ W[256,256] fp32 -> bf16.
// Head-major outputs: Qh/Kh [B*H][S][32], Vt transposed [B*H][32][S].
// 16 rows/block (512 blocks) halves W L2 traffic vs 8 rows/block.
// ---------------------------------------------------------------------------
__global__ __launch_bounds__(512) void qkv_proj_kernel(
    const float* __restrict__ x,
    const float* __restrict__ Wq, const float* __restrict__ bq,
    const float* __restrict__ Wk, const float* __restrict__ bk,
    const float* __restrict__ Wv, const float* __restrict__ bv,
    unsigned short* __restrict__ Qh, unsigned short* __restrict__ Kh,
    unsigned short* __restrict__ Vt)
{
    __shared__ float xs[16][D_MODEL];          // 16 KB
    __shared__ unsigned short vs[D_MODEL][16]; // 8 KB (bf16 V tile for transpose)
    const int tid = threadIdx.x;
    const int row0 = blockIdx.x * 16;

    {   // stage 16 rows x 256 fp32 = 1024 float4; 512 threads x 2
        const float4* src = (const float4*)(x + (size_t)row0 * D_MODEL);
        float4* dst = (float4*)xs;
        dst[tid]       = src[tid];
        dst[tid + 512] = src[tid + 512];
    }
    __syncthreads();

    const int n  = tid & 255;        // output column
    const int rg = (tid >> 8) * 8;   // rows rg..rg+7

    float aq[8] = {0,0,0,0,0,0,0,0};
    float ak[8] = {0,0,0,0,0,0,0,0};
    float av[8] = {0,0,0,0,0,0,0,0};
    for (int k = 0; k < D_MODEL; k++) {
        const float wq = Wq[(k << 8) + n];
        const float wk = Wk[(k << 8) + n];
        const float wv = Wv[(k << 8) + n];
        #pragma unroll
        for (int r = 0; r < 8; r++) {
            const float xr = xs[rg + r][k];   // wave-uniform broadcast read
            aq[r] = fmaf(xr, wq, aq[r]);
            ak[r] = fmaf(xr, wk, ak[r]);
            av[r] = fmaf(xr, wv, av[r]);
        }
    }

    const float bqn = bq[n], bkn = bk[n], bvn = bv[n];
    const int h = n >> 5, d = n & 31;

    #pragma unroll
    for (int r = 0; r < 8; r++) {
        const int rr = row0 + rg + r;
        const int bb = rr >> 12;
        const int s  = rr & (SEQ - 1);
        const size_t bh = (size_t)(bb * NUM_HEADS + h);
        Qh[(bh * SEQ + s) * DIM_HEAD + d] = f2b(aq[r] + bqn);
        Kh[(bh * SEQ + s) * DIM_HEAD + d] = f2b(ak[r] + bkn);
        vs[n][rg + r] = f2b(av[r] + bvn);
    }
    __syncthreads();

    if (tid < 256) {
        // column tid: vs[tid][0..15] -> Vt row (bh*32+d), 16 seq pos, 2x16B
        const int h2 = tid >> 5, d2 = tid & 31;
        const int bb = row0 >> 12;               // 16-row blocks never straddle batch
        const int s  = row0 & (SEQ - 1);
        const size_t bh = (size_t)(bb * NUM_HEADS + h2);
        unsigned short* dst = Vt + (bh * DIM_HEAD + d2) * SEQ + s;
        *(uint4*)dst       = *(const uint4*)&vs[tid][0];
        *(uint4*)(dst + 8) = *(const uint4*)&vs[tid][8];
    }
}

// ---------------------------------------------------------------------------
// Kernel 1b: additive mask term in exp2 domain: T2 = pad * (-1e9*scale*log2e)
// ---------------------------------------------------------------------------
__global__ __launch_bounds__(256) void maskT_kernel(
    const float* __restrict__ pad, float* __restrict__ T2)
{
    const int i = blockIdx.x * 256 + threadIdx.x;
    T2[i] = pad[i] * (MASK_BIAS * SCALE * LOG2E);
}

// ---------------------------------------------------------------------------
// Kernel 2: MFMA flash attention, register-only P transpose.
// KEY TRICK: QK^T's A operand (K rows) is fed PERMUTED: tile0 row m <- key
// pi(m)=8*(m>>2)+(m&3), tile1 row m <- pi(m)+4. Then lane (c,quad)'s 8 score
// regs [st0 r0..3, st1 r0..3] hold keys s0+8*quad+{0..7} — exactly the PV
// B-fragment slice (B[k=quad*8+j][n=c]). No LDS round-trip, no conflicts.
// One q-tile (16 queries) per block; 4 waves split the keys; linear combine.
// ---------------------------------------------------------------------------
__global__ __launch_bounds__(256) void attn_mfma_kernel(
    const unsigned short* __restrict__ Qh, const unsigned short* __restrict__ Kh,
    const unsigned short* __restrict__ Vt, const float* __restrict__ T2,
    float* __restrict__ O)
{
    __shared__ float part[4][64][12];            // per-wave partials (o0,o1,l)

    const int lane = threadIdx.x & 63;
    const int wid  = threadIdx.x >> 6;
    const int c    = lane & 15;                  // query col / dim row
    const int quad = lane >> 4;

    const int gw = blockIdx.x;                   // 0..4095: one q-tile
    const int q0 = (gw & 255) * 16;
    const int h  = (gw >> 8) & (NUM_HEADS - 1);
    const int b  = gw >> 11;
    const size_t bh = (size_t)(b * NUM_HEADS + h);

    const float k2 = SCALE * LOG2E;              // dot -> exp2-domain score
    const int perm = ((c & 12) << 1) | (c & 3);  // pi(c): key row for tile0

    // B-fragment of Q (loop-invariant): B[k=d][n=query]
    const short8 qf = *(const short8*)(Qh + (bh * SEQ + q0 + c) * DIM_HEAD + quad * 8);

    const unsigned short* Kb = Kh + bh * SEQ * DIM_HEAD;
    const unsigned short* Vb = Vt + bh * DIM_HEAD * SEQ;
    const float* Tb = T2 + (size_t)b * SEQ;

    f32x4 o0 = {0.f, 0.f, 0.f, 0.f};
    f32x4 o1 = {0.f, 0.f, 0.f, 0.f};
    float l = 0.f;

    const int sbeg = wid * (SEQ / 4);
    #pragma unroll 4
    for (int s0 = sbeg; s0 < sbeg + SEQ / 4; s0 += 32) {
        // --- K rows, permuted so C-layout == PV B-frag layout
        const short8 kf0 = *(const short8*)(Kb + (size_t)(s0 + perm)     * DIM_HEAD + quad * 8);
        const short8 kf1 = *(const short8*)(Kb + (size_t)(s0 + perm + 4) * DIM_HEAD + quad * 8);
        const f32x4 z = {0.f, 0.f, 0.f, 0.f};
        const f32x4 st0 = __builtin_amdgcn_mfma_f32_16x16x32_bf16(kf0, qf, z, 0, 0, 0);
        const f32x4 st1 = __builtin_amdgcn_mfma_f32_16x16x32_bf16(kf1, qf, z, 0, 0, 0);

        // mask terms for this lane's keys: s0 + quad*8 + {0..7}
        const float4 t0 = *(const float4*)(Tb + s0 + quad * 8);
        const float4 t1 = *(const float4*)(Tb + s0 + quad * 8 + 4);

        // --- p = exp2(score), no max subtraction (scores bounded)
        float p[8];
        p[0] = exp2f(fmaf(st0[0], k2, t0.x));
        p[1] = exp2f(fmaf(st0[1], k2, t0.y));
        p[2] = exp2f(fmaf(st0[2], k2, t0.z));
        p[3] = exp2f(fmaf(st0[3], k2, t0.w));
        p[4] = exp2f(fmaf(st1[0], k2, t1.x));
        p[5] = exp2f(fmaf(st1[1], k2, t1.y));
        p[6] = exp2f(fmaf(st1[2], k2, t1.z));
        p[7] = exp2f(fmaf(st1[3], k2, t1.w));
        l += ((p[0] + p[1]) + (p[2] + p[3])) + ((p[4] + p[5]) + (p[6] + p[7]));

        // --- PV B-fragment built directly in registers (keys quad*8+j)
        union { unsigned int u[4]; short8 s; } pf;
        pf.u[0] = pk_bf16(p[0], p[1]);
        pf.u[1] = pk_bf16(p[2], p[3]);
        pf.u[2] = pk_bf16(p[4], p[5]);
        pf.u[3] = pk_bf16(p[6], p[7]);

        // --- O^T += V^T x P^T  (A: V^T[dim=c][key=s0+quad*8+j], 16B loads)
        const short8 vf0 = *(const short8*)(Vb + (size_t)c        * SEQ + s0 + quad * 8);
        const short8 vf1 = *(const short8*)(Vb + (size_t)(16 + c) * SEQ + s0 + quad * 8);
        o0 = __builtin_amdgcn_mfma_f32_16x16x32_bf16(vf0, pf.s, o0, 0, 0, 0);
        o1 = __builtin_amdgcn_mfma_f32_16x16x32_bf16(vf1, pf.s, o1, 0, 0, 0);
    }

    // --- reduce l across quads -> full per-query sum for this wave
    l += __shfl_xor(l, 16, 64);
    l += __shfl_xor(l, 32, 64);

    // --- combine the 4 waves' partials (linear: no max, no rescale)
    *(f32x4*)&part[wid][lane][0] = o0;
    *(f32x4*)&part[wid][lane][4] = o1;
    part[wid][lane][8] = l;
    __syncthreads();

    if (wid == 0) {
        f32x4 a0 = {0.f, 0.f, 0.f, 0.f};
        f32x4 a1 = {0.f, 0.f, 0.f, 0.f};
        float L = 0.f;
        #pragma unroll
        for (int w = 0; w < 4; w++) {
            const f32x4 u0 = *(const f32x4*)&part[w][lane][0];
            const f32x4 u1 = *(const f32x4*)&part[w][lane][4];
            #pragma unroll
            for (int i = 0; i < 4; i++) { a0[i] += u0[i]; a1[i] += u1[i]; }
            L += part[w][lane][8];
        }
        const float inv = 1.0f / L;
        float* op = O + ((size_t)(b * SEQ) + q0 + c) * D_MODEL + h * DIM_HEAD + quad * 4;
        *(float4*)op        = make_float4(a0[0]*inv, a0[1]*inv, a0[2]*inv, a0[3]*inv);
        *(float4*)(op + 16) = make_float4(a1[0]*inv, a1[1]*inv, a1[2]*inv, a1[3]*inv);
    }
}

// ---------------------------------------------------------------------------
// Kernel 3: residual add + LayerNorm IN PLACE on d_out (fp32 -> fp32).
// ---------------------------------------------------------------------------
__global__ __launch_bounds__(256) void ln_kernel(
    float* AO,                     // aliased read A / write out — no restrict
    const float* __restrict__ x,
    const float* __restrict__ gamma, const float* __restrict__ beta)
{
    const int lane = threadIdx.x & 63;
    const int wid  = threadIdx.x >> 6;
    const size_t row = (size_t)blockIdx.x * 4 + wid;

    const float4 a  = ((const float4*)(AO + row * D_MODEL))[lane];
    const float4 xv = ((const float4*)(x + row * D_MODEL))[lane];
    float hv[4];
    hv[0] = a.x + xv.x;
    hv[1] = a.y + xv.y;
    hv[2] = a.z + xv.z;
    hv[3] = a.w + xv.w;

    float s = hv[0] + hv[1] + hv[2] + hv[3];
    #pragma unroll
    for (int off = 32; off > 0; off >>= 1) s += __shfl_xor(s, off, 64);
    const float mu = s * (1.0f / D_MODEL);

    float d0 = hv[0]-mu, d1 = hv[1]-mu, d2 = hv[2]-mu, d3 = hv[3]-mu;
    float ss = d0*d0 + d1*d1 + d2*d2 + d3*d3;
    #pragma unroll
    for (int off = 32; off > 0; off >>= 1) ss += __shfl_xor(ss, off, 64);
    const float rs = rsqrtf(ss * (1.0f / D_MODEL) + LN_EPS);

    const float4 g  = ((const float4*)gamma)[lane];
    const float4 bb = ((const float4*)beta)[lane];
    float4 y;
    y.x = g.x * d0 * rs + bb.x;
    y.y = g.y * d1 * rs + bb.y;
    y.z = g.z * d2 * rs + bb.z;
    y.w = g.w * d3 * rs + bb.w;
    ((float4*)(AO + row * D_MODEL))[lane] = y;
}

// ---------------------------------------------------------------------------
extern "C" void kernel_launch(void* const* d_in, const int* in_sizes, int n_in,
                              void* d_out, int out_size, void* d_ws, size_t ws_size,
                              hipStream_t stream)
{
    const float* x     = (const float*)d_in[0];
    const float* pad   = (const float*)d_in[1];
    const float* Wq    = (const float*)d_in[2];
    const float* bq    = (const float*)d_in[3];
    const float* Wk    = (const float*)d_in[4];
    const float* bk    = (const float*)d_in[5];
    const float* Wv    = (const float*)d_in[6];
    const float* bv    = (const float*)d_in[7];
    const float* gamma = (const float*)d_in[8];
    const float* beta  = (const float*)d_in[9];

    const size_t elems = (size_t)NROWS * D_MODEL;       // 2M
    unsigned short* Qh = (unsigned short*)d_ws;          // 4 MB
    unsigned short* Kh = Qh + elems;                     // 4 MB
    unsigned short* Vt = Kh + elems;                     // 4 MB
    float* T2 = (float*)(Vt + elems);                    // 32 KB
    float* AO = (float*)d_out;                           // attn out + final out

    qkv_proj_kernel<<<NROWS / 16, 512, 0, stream>>>(x, Wq, bq, Wk, bk, Wv, bv,
                                                    Qh, Kh, Vt);
    maskT_kernel<<<NROWS / 256, 256, 0, stream>>>(pad, T2);
    attn_mfma_kernel<<<BATCH * NUM_HEADS * (SEQ / 16), 256, 0, stream>>>(
        Qh, Kh, Vt, T2, AO);
    ln_kernel<<<NROWS / 4, 256, 0, stream>>>(AO, x, gamma, beta);
}

// Round 10
// 239.941 us; speedup vs baseline: 1.4342x; 1.4342x over previous
//
#include <hip/hip_runtime.h>
#include <hip/hip_bf16.h>

#define D_MODEL 256
#define NUM_HEADS 8
#define DIM_HEAD 32
#define SEQ 4096
#define BATCH 2
#define NROWS (BATCH * SEQ)              // 8192
#define LN_EPS 1e-6f
#define MASK_BIAS -1.0e9f
#define SCALE 0.17677669529663687f      // 1/sqrt(32)
#define LOG2E 1.4426950408889634f

typedef __attribute__((ext_vector_type(8))) short short8;   // 8 bf16 (4 VGPRs)
typedef __attribute__((ext_vector_type(4))) float f32x4;    // MFMA C/D

// fp32 -> bf16 bits (RNE)
static __device__ __forceinline__ unsigned short f2b(float f) {
    union { __hip_bfloat16 b; unsigned short u; } cv;
    cv.b = __float2bfloat16(f);
    return cv.u;
}
// packed fp32 pair -> bf16x2 (RNE), lo in low 16 bits
static __device__ __forceinline__ unsigned int pk_bf16(float lo, float hi) {
    union { __hip_bfloat162 v; unsigned int u; } cv;
    cv.v = __float22bfloat162_rn(make_float2(lo, hi));
    return cv.u;
}

// ---------------------------------------------------------------------------
// Kernel 1: fused QKV projection. x[8192,256] fp32 @ W[256,256] fp32 -> bf16.
// Head-major outputs: Qh/Kh [B*H][S][32], Vt transposed [B*H][32][S].
// ---------------------------------------------------------------------------
__global__ __launch_bounds__(512) void qkv_proj_kernel(
    const float* __restrict__ x,
    const float* __restrict__ Wq, const float* __restrict__ bq,
    const float* __restrict__ Wk, const float* __restrict__ bk,
    const float* __restrict__ Wv, const float* __restrict__ bv,
    unsigned short* __restrict__ Qh, unsigned short* __restrict__ Kh,
    unsigned short* __restrict__ Vt)
{
    __shared__ float xs[16][D_MODEL];          // 16 KB
    __shared__ unsigned short vs[D_MODEL][16]; // 8 KB (bf16 V tile for transpose)
    const int tid = threadIdx.x;
    const int row0 = blockIdx.x * 16;

    {   // stage 16 rows x 256 fp32 = 1024 float4; 512 threads x 2
        const float4* src = (const float4*)(x + (size_t)row0 * D_MODEL);
        float4* dst = (float4*)xs;
        dst[tid]       = src[tid];
        dst[tid + 512] = src[tid + 512];
    }
    __syncthreads();

    const int n  = tid & 255;        // output column
    const int rg = (tid >> 8) * 8;   // rows rg..rg+7

    float aq[8] = {0,0,0,0,0,0,0,0};
    float ak[8] = {0,0,0,0,0,0,0,0};
    float av[8] = {0,0,0,0,0,0,0,0};
    for (int k = 0; k < D_MODEL; k++) {
        const float wq = Wq[(k << 8) + n];
        const float wk = Wk[(k << 8) + n];
        const float wv = Wv[(k << 8) + n];
        #pragma unroll
        for (int r = 0; r < 8; r++) {
            const float xr = xs[rg + r][k];   // wave-uniform broadcast read
            aq[r] = fmaf(xr, wq, aq[r]);
            ak[r] = fmaf(xr, wk, ak[r]);
            av[r] = fmaf(xr, wv, av[r]);
        }
    }

    const float bqn = bq[n], bkn = bk[n], bvn = bv[n];
    const int h = n >> 5, d = n & 31;

    #pragma unroll
    for (int r = 0; r < 8; r++) {
        const int rr = row0 + rg + r;
        const int bb = rr >> 12;
        const int s  = rr & (SEQ - 1);
        const size_t bh = (size_t)(bb * NUM_HEADS + h);
        Qh[(bh * SEQ + s) * DIM_HEAD + d] = f2b(aq[r] + bqn);
        Kh[(bh * SEQ + s) * DIM_HEAD + d] = f2b(ak[r] + bkn);
        vs[n][rg + r] = f2b(av[r] + bvn);
    }
    __syncthreads();

    if (tid < 256) {
        // column tid: vs[tid][0..15] -> Vt row (bh*32+d), 16 seq pos, 2x16B
        const int h2 = tid >> 5, d2 = tid & 31;
        const int bb = row0 >> 12;               // 16-row blocks never straddle batch
        const int s  = row0 & (SEQ - 1);
        const size_t bh = (size_t)(bb * NUM_HEADS + h2);
        unsigned short* dst = Vt + (bh * DIM_HEAD + d2) * SEQ + s;
        *(uint4*)dst       = *(const uint4*)&vs[tid][0];
        *(uint4*)(dst + 8) = *(const uint4*)&vs[tid][8];
    }
}

// ---------------------------------------------------------------------------
// Kernel 1b: additive mask term in exp2 domain: T2 = pad * (-1e9*scale*log2e)
// ---------------------------------------------------------------------------
__global__ __launch_bounds__(256) void maskT_kernel(
    const float* __restrict__ pad, float* __restrict__ T2)
{
    const int i = blockIdx.x * 256 + threadIdx.x;
    T2[i] = pad[i] * (MASK_BIAS * SCALE * LOG2E);
}

// ---------------------------------------------------------------------------
// Kernel 2: MFMA flash attention v3.
// Wave = 32 queries (2 Q-fragments sharing every K/V load -> 8 MFMAs per
// 32-key chunk, two independent chains). Block = 64 queries: wave pair
// (wid>>1) owns 32 queries, parity (wid&1) owns half the keys; pair partials
// combine linearly through LDS. Explicit 1-iteration register prefetch of
// the 6 loads to cover L2 latency. Register-only P transpose via permuted
// K rows: pi(m)=8*(m>>2)+(m&3) (tile0), +4 (tile1) => lane (c,quad) scores
// are keys s0+8*quad+{0..7} == PV B-frag slice.
// ---------------------------------------------------------------------------
__global__ __launch_bounds__(256) void attn_mfma_kernel(
    const unsigned short* __restrict__ Qh, const unsigned short* __restrict__ Kh,
    const unsigned short* __restrict__ Vt, const float* __restrict__ T2,
    float* __restrict__ O)
{
    __shared__ float part[4][64][20];            // o0A,o1A,o0B,o1B,lA,lB (+pad)

    const int lane = threadIdx.x & 63;
    const int wid  = threadIdx.x >> 6;
    const int c    = lane & 15;                  // query col / dim row
    const int quad = lane >> 4;

    const int gw = blockIdx.x;                   // 0..1023
    const int q0 = (gw & 63) * 64;               // 64 queries per block
    const int h  = (gw >> 6) & (NUM_HEADS - 1);
    const int b  = gw >> 9;
    const size_t bh = (size_t)(b * NUM_HEADS + h);

    const int pairq = (wid >> 1) * 32;           // this pair's query base
    const int e     = wid & 1;                   // key half

    const float k2 = SCALE * LOG2E;              // dot -> exp2-domain score
    const int perm = ((c & 12) << 1) | (c & 3);  // pi(c)

    // Two loop-invariant Q B-fragments (queries qb+c and qb+16+c)
    const int qb = q0 + pairq;
    const short8 qfA = *(const short8*)(Qh + (bh * SEQ + qb + c)      * DIM_HEAD + quad * 8);
    const short8 qfB = *(const short8*)(Qh + (bh * SEQ + qb + 16 + c) * DIM_HEAD + quad * 8);

    const unsigned short* Kb = Kh + bh * SEQ * DIM_HEAD;
    const unsigned short* Vb = Vt + bh * DIM_HEAD * SEQ;
    const float* Tb = T2 + (size_t)b * SEQ;

    f32x4 o0A = {0.f,0.f,0.f,0.f}, o1A = {0.f,0.f,0.f,0.f};
    f32x4 o0B = {0.f,0.f,0.f,0.f}, o1B = {0.f,0.f,0.f,0.f};
    float lA = 0.f, lB = 0.f;

    const int sbeg = e * (SEQ / 2);
    const int send = sbeg + SEQ / 2;

    // ---- prolog: load chunk at sbeg
    short8 kf0 = *(const short8*)(Kb + (size_t)(sbeg + perm)     * DIM_HEAD + quad * 8);
    short8 kf1 = *(const short8*)(Kb + (size_t)(sbeg + perm + 4) * DIM_HEAD + quad * 8);
    short8 vf0 = *(const short8*)(Vb + (size_t)c        * SEQ + sbeg + quad * 8);
    short8 vf1 = *(const short8*)(Vb + (size_t)(16 + c) * SEQ + sbeg + quad * 8);
    float4 t0 = *(const float4*)(Tb + sbeg + quad * 8);
    float4 t1 = *(const float4*)(Tb + sbeg + quad * 8 + 4);

    const f32x4 z = {0.f, 0.f, 0.f, 0.f};

    for (int s0 = sbeg; s0 < send; s0 += 32) {
        // ---- prefetch next chunk (wraps to sbeg on last iter; discarded)
        int sn = s0 + 32; if (sn == send) sn = sbeg;
        const short8 nk0 = *(const short8*)(Kb + (size_t)(sn + perm)     * DIM_HEAD + quad * 8);
        const short8 nk1 = *(const short8*)(Kb + (size_t)(sn + perm + 4) * DIM_HEAD + quad * 8);
        const short8 nv0 = *(const short8*)(Vb + (size_t)c        * SEQ + sn + quad * 8);
        const short8 nv1 = *(const short8*)(Vb + (size_t)(16 + c) * SEQ + sn + quad * 8);
        const float4 nt0 = *(const float4*)(Tb + sn + quad * 8);
        const float4 nt1 = *(const float4*)(Tb + sn + quad * 8 + 4);

        // ---- scores for both q-frags (K rows shared)
        const f32x4 s0A = __builtin_amdgcn_mfma_f32_16x16x32_bf16(kf0, qfA, z, 0, 0, 0);
        const f32x4 s1A = __builtin_amdgcn_mfma_f32_16x16x32_bf16(kf1, qfA, z, 0, 0, 0);
        const f32x4 s0B = __builtin_amdgcn_mfma_f32_16x16x32_bf16(kf0, qfB, z, 0, 0, 0);
        const f32x4 s1B = __builtin_amdgcn_mfma_f32_16x16x32_bf16(kf1, qfB, z, 0, 0, 0);

        // ---- p = exp2(score*k2 + mask), keys s0+8*quad+{0..7}
        float pA[8], pB[8];
        pA[0] = exp2f(fmaf(s0A[0], k2, t0.x));
        pA[1] = exp2f(fmaf(s0A[1], k2, t0.y));
        pA[2] = exp2f(fmaf(s0A[2], k2, t0.z));
        pA[3] = exp2f(fmaf(s0A[3], k2, t0.w));
        pA[4] = exp2f(fmaf(s1A[0], k2, t1.x));
        pA[5] = exp2f(fmaf(s1A[1], k2, t1.y));
        pA[6] = exp2f(fmaf(s1A[2], k2, t1.z));
        pA[7] = exp2f(fmaf(s1A[3], k2, t1.w));
        pB[0] = exp2f(fmaf(s0B[0], k2, t0.x));
        pB[1] = exp2f(fmaf(s0B[1], k2, t0.y));
        pB[2] = exp2f(fmaf(s0B[2], k2, t0.z));
        pB[3] = exp2f(fmaf(s0B[3], k2, t0.w));
        pB[4] = exp2f(fmaf(s1B[0], k2, t1.x));
        pB[5] = exp2f(fmaf(s1B[1], k2, t1.y));
        pB[6] = exp2f(fmaf(s1B[2], k2, t1.z));
        pB[7] = exp2f(fmaf(s1B[3], k2, t1.w));
        lA += ((pA[0]+pA[1]) + (pA[2]+pA[3])) + ((pA[4]+pA[5]) + (pA[6]+pA[7]));
        lB += ((pB[0]+pB[1]) + (pB[2]+pB[3])) + ((pB[4]+pB[5]) + (pB[6]+pB[7]));

        // ---- PV B-fragments in registers
        union { unsigned int u[4]; short8 s; } pfA, pfB;
        pfA.u[0] = pk_bf16(pA[0], pA[1]);
        pfA.u[1] = pk_bf16(pA[2], pA[3]);
        pfA.u[2] = pk_bf16(pA[4], pA[5]);
        pfA.u[3] = pk_bf16(pA[6], pA[7]);
        pfB.u[0] = pk_bf16(pB[0], pB[1]);
        pfB.u[1] = pk_bf16(pB[2], pB[3]);
        pfB.u[2] = pk_bf16(pB[4], pB[5]);
        pfB.u[3] = pk_bf16(pB[6], pB[7]);

        // ---- O^T += V^T x P^T (V rows shared by both q-frags)
        o0A = __builtin_amdgcn_mfma_f32_16x16x32_bf16(vf0, pfA.s, o0A, 0, 0, 0);
        o1A = __builtin_amdgcn_mfma_f32_16x16x32_bf16(vf1, pfA.s, o1A, 0, 0, 0);
        o0B = __builtin_amdgcn_mfma_f32_16x16x32_bf16(vf0, pfB.s, o0B, 0, 0, 0);
        o1B = __builtin_amdgcn_mfma_f32_16x16x32_bf16(vf1, pfB.s, o1B, 0, 0, 0);

        // ---- rotate prefetched registers
        kf0 = nk0; kf1 = nk1; vf0 = nv0; vf1 = nv1; t0 = nt0; t1 = nt1;
    }

    // ---- quad-reduce l (per-lane l covers 8 of each 32-key chunk)
    lA += __shfl_xor(lA, 16, 64); lA += __shfl_xor(lA, 32, 64);
    lB += __shfl_xor(lB, 16, 64); lB += __shfl_xor(lB, 32, 64);

    // ---- combine key-parity mates (linear: no max, no rescale)
    *(f32x4*)&part[wid][lane][0]  = o0A;
    *(f32x4*)&part[wid][lane][4]  = o1A;
    *(f32x4*)&part[wid][lane][8]  = o0B;
    *(f32x4*)&part[wid][lane][12] = o1B;
    part[wid][lane][16] = lA;
    part[wid][lane][17] = lB;
    __syncthreads();

    if (e == 0) {
        const int mate = wid + 1;
        const f32x4 m0A = *(const f32x4*)&part[mate][lane][0];
        const f32x4 m1A = *(const f32x4*)&part[mate][lane][4];
        const f32x4 m0B = *(const f32x4*)&part[mate][lane][8];
        const f32x4 m1B = *(const f32x4*)&part[mate][lane][12];
        const float invA = 1.0f / (lA + part[mate][lane][16]);
        const float invB = 1.0f / (lB + part[mate][lane][17]);

        float* opA = O + ((size_t)(b * SEQ) + qb + c) * D_MODEL + h * DIM_HEAD + quad * 4;
        *(float4*)opA        = make_float4((o0A[0]+m0A[0])*invA, (o0A[1]+m0A[1])*invA,
                                           (o0A[2]+m0A[2])*invA, (o0A[3]+m0A[3])*invA);
        *(float4*)(opA + 16) = make_float4((o1A[0]+m1A[0])*invA, (o1A[1]+m1A[1])*invA,
                                           (o1A[2]+m1A[2])*invA, (o1A[3]+m1A[3])*invA);
        float* opB = opA + 16 * D_MODEL;     // query qb+16+c
        *(float4*)opB        = make_float4((o0B[0]+m0B[0])*invB, (o0B[1]+m0B[1])*invB,
                                           (o0B[2]+m0B[2])*invB, (o0B[3]+m0B[3])*invB);
        *(float4*)(opB + 16) = make_float4((o1B[0]+m1B[0])*invB, (o1B[1]+m1B[1])*invB,
                                           (o1B[2]+m1B[2])*invB, (o1B[3]+m1B[3])*invB);
    }
}

// ---------------------------------------------------------------------------
// Kernel 3: residual add + LayerNorm IN PLACE on d_out (fp32 -> fp32).
// ---------------------------------------------------------------------------
__global__ __launch_bounds__(256) void ln_kernel(
    float* AO,                     // aliased read A / write out — no restrict
    const float* __restrict__ x,
    const float* __restrict__ gamma, const float* __restrict__ beta)
{
    const int lane = threadIdx.x & 63;
    const int wid  = threadIdx.x >> 6;
    const size_t row = (size_t)blockIdx.x * 4 + wid;

    const float4 a  = ((const float4*)(AO + row * D_MODEL))[lane];
    const float4 xv = ((const float4*)(x + row * D_MODEL))[lane];
    float hv[4];
    hv[0] = a.x + xv.x;
    hv[1] = a.y + xv.y;
    hv[2] = a.z + xv.z;
    hv[3] = a.w + xv.w;

    float s = hv[0] + hv[1] + hv[2] + hv[3];
    #pragma unroll
    for (int off = 32; off > 0; off >>= 1) s += __shfl_xor(s, off, 64);
    const float mu = s * (1.0f / D_MODEL);

    float d0 = hv[0]-mu, d1 = hv[1]-mu, d2 = hv[2]-mu, d3 = hv[3]-mu;
    float ss = d0*d0 + d1*d1 + d2*d2 + d3*d3;
    #pragma unroll
    for (int off = 32; off > 0; off >>= 1) ss += __shfl_xor(ss, off, 64);
    const float rs = rsqrtf(ss * (1.0f / D_MODEL) + LN_EPS);

    const float4 g  = ((const float4*)gamma)[lane];
    const float4 bb = ((const float4*)beta)[lane];
    float4 y;
    y.x = g.x * d0 * rs + bb.x;
    y.y = g.y * d1 * rs + bb.y;
    y.z = g.z * d2 * rs + bb.z;
    y.w = g.w * d3 * rs + bb.w;
    ((float4*)(AO + row * D_MODEL))[lane] = y;
}

// ---------------------------------------------------------------------------
extern "C" void kernel_launch(void* const* d_in, const int* in_sizes, int n_in,
                              void* d_out, int out_size, void* d_ws, size_t ws_size,
                              hipStream_t stream)
{
    const float* x     = (const float*)d_in[0];
    const float* pad   = (const float*)d_in[1];
    const float* Wq    = (const float*)d_in[2];
    const float* bq    = (const float*)d_in[3];
    const float* Wk    = (const float*)d_in[4];
    const float* bk    = (const float*)d_in[5];
    const float* Wv    = (const float*)d_in[6];
    const float* bv    = (const float*)d_in[7];
    const float* gamma = (const float*)d_in[8];
    const float* beta  = (const float*)d_in[9];

    const size_t elems = (size_t)NROWS * D_MODEL;       // 2M
    unsigned short* Qh = (unsigned short*)d_ws;          // 4 MB
    unsigned short* Kh = Qh + elems;                     // 4 MB
    unsigned short* Vt = Kh + elems;                     // 4 MB
    float* T2 = (float*)(Vt + elems);                    // 32 KB
    float* AO = (float*)d_out;                           // attn out + final out

    qkv_proj_kernel<<<NROWS / 16, 512, 0, stream>>>(x, Wq, bq, Wk, bk, Wv, bv,
                                                    Qh, Kh, Vt);
    maskT_kernel<<<NROWS / 256, 256, 0, stream>>>(pad, T2);
    attn_mfma_kernel<<<BATCH * NUM_HEADS * (SEQ / 64), 256, 0, stream>>>(
        Qh, Kh, Vt, T2, AO);
    ln_kernel<<<NROWS / 4, 256, 0, stream>>>(AO, x, gamma, beta);
}

// Round 11
// 224.067 us; speedup vs baseline: 1.5358x; 1.0708x over previous
//
#include <hip/hip_runtime.h>
#include <hip/hip_bf16.h>

#define D_MODEL 256
#define NUM_HEADS 8
#define DIM_HEAD 32
#define SEQ 4096
#define BATCH 2
#define NROWS (BATCH * SEQ)              // 8192
#define LN_EPS 1e-6f
#define MASK_BIAS -1.0e9f
#define SCALE 0.17677669529663687f      // 1/sqrt(32)
#define LOG2E 1.4426950408889634f

typedef __attribute__((ext_vector_type(8))) short short8;   // 8 bf16 (4 VGPRs)
typedef __attribute__((ext_vector_type(4))) float f32x4;    // MFMA C/D

// fp32 -> bf16 bits (RNE)
static __device__ __forceinline__ unsigned short f2b(float f) {
    union { __hip_bfloat16 b; unsigned short u; } cv;
    cv.b = __float2bfloat16(f);
    return cv.u;
}
// packed fp32 pair -> bf16x2 (RNE), lo in low 16 bits
static __device__ __forceinline__ unsigned int pk_bf16(float lo, float hi) {
    union { __hip_bfloat162 v; unsigned int u; } cv;
    cv.v = __float22bfloat162_rn(make_float2(lo, hi));
    return cv.u;
}

// ---------------------------------------------------------------------------
// Kernel 0: prep. Blocks 0..767: Wt[n_cat][k] = W_w[k][n] (bf16) + bias concat.
// Blocks 768..799: T2 = pad * (-1e9*scale*log2e).
// ---------------------------------------------------------------------------
__global__ __launch_bounds__(256) void prep_kernel(
    const float* __restrict__ Wq, const float* __restrict__ Wk,
    const float* __restrict__ Wv,
    const float* __restrict__ bq, const float* __restrict__ bk,
    const float* __restrict__ bv,
    const float* __restrict__ pad,
    unsigned short* __restrict__ Wt, float* __restrict__ biasc,
    float* __restrict__ T2)
{
    const int blk = blockIdx.x;
    const int t = threadIdx.x;
    if (blk < 768) {
        const int w = blk >> 8;          // 0=Q 1=K 2=V
        const int n = blk & 255;         // output column
        const float* W = (w == 0) ? Wq : (w == 1) ? Wk : Wv;
        Wt[(size_t)blk * 256 + t] = f2b(W[(size_t)t * 256 + n]);
        if (t == 0) {
            const float* bb = (w == 0) ? bq : (w == 1) ? bk : bv;
            biasc[blk] = bb[n];
        }
    } else {
        const int i = (blk - 768) * 256 + t;
        T2[i] = pad[i] * (MASK_BIAS * SCALE * LOG2E);
    }
}

// ---------------------------------------------------------------------------
// Kernel 1: QKV projection as bf16 MFMA GEMM. C = x[8192,256] @ Wt^T[256,768].
// Block = 4 waves = 64 rows x 96 cols; wave = 16 rows x 6 col-tiles.
// A-frag: x fp32 loaded 32B/lane, packed to bf16 in-flight. B-frag: Wt 16B.
// Epilogue: +bias, bf16, route per col: Q/K row-major, V transposed (8B).
// 256-col boundaries align with 16-col tiles, so each tile is one matrix.
// ---------------------------------------------------------------------------
__global__ __launch_bounds__(256) void qkv_mfma_kernel(
    const float* __restrict__ x, const unsigned short* __restrict__ Wt,
    const float* __restrict__ biasc,
    unsigned short* __restrict__ Qh, unsigned short* __restrict__ Kh,
    unsigned short* __restrict__ Vt)
{
    const int lane = threadIdx.x & 63;
    const int wid  = threadIdx.x >> 6;
    const int c    = lane & 15;
    const int quad = lane >> 4;

    const int r0 = (blockIdx.x >> 3) * 64 + wid * 16;   // wave row base
    const int n0 = (blockIdx.x & 7) * 96;               // wave col base

    f32x4 acc[6];
    float bias[6];
    #pragma unroll
    for (int t = 0; t < 6; t++) {
        acc[t] = (f32x4){0.f, 0.f, 0.f, 0.f};
        bias[t] = biasc[n0 + 16 * t + c];
    }

    const float* xp0 = x + (size_t)(r0 + c) * D_MODEL + quad * 8;
    const unsigned short* wp0 = Wt + (size_t)(n0 + c) * 256 + quad * 8;

    for (int k0 = 0; k0 < 256; k0 += 32) {
        const float4 a0 = *(const float4*)(xp0 + k0);
        const float4 a1 = *(const float4*)(xp0 + k0 + 4);
        union { unsigned int u[4]; short8 s; } af;
        af.u[0] = pk_bf16(a0.x, a0.y);
        af.u[1] = pk_bf16(a0.z, a0.w);
        af.u[2] = pk_bf16(a1.x, a1.y);
        af.u[3] = pk_bf16(a1.z, a1.w);
        #pragma unroll
        for (int t = 0; t < 6; t++) {
            const short8 bf = *(const short8*)(wp0 + (size_t)(16 * t) * 256 + k0);
            acc[t] = __builtin_amdgcn_mfma_f32_16x16x32_bf16(af.s, bf, acc[t], 0, 0, 0);
        }
    }

    #pragma unroll
    for (int t = 0; t < 6; t++) {
        const int col = n0 + 16 * t;          // tile col base (multiple of 16)
        const int mm  = col >> 8;             // 0=Q 1=K 2=V (uniform per tile)
        const int dim = (col & 255) + c;
        const int h = dim >> 5, d = dim & 31;
        const int row = r0 + quad * 4;        // rows row..row+3 (same batch)
        const int bb = row >> 12;
        const int s  = row & (SEQ - 1);
        const size_t bh = (size_t)(bb * NUM_HEADS + h);
        const float v0 = acc[t][0] + bias[t];
        const float v1 = acc[t][1] + bias[t];
        const float v2 = acc[t][2] + bias[t];
        const float v3 = acc[t][3] + bias[t];
        if (mm == 2) {
            uint2 pk = make_uint2(pk_bf16(v0, v1), pk_bf16(v2, v3));
            *(uint2*)(Vt + (bh * DIM_HEAD + d) * SEQ + s) = pk;
        } else {
            unsigned short* P = (mm == 0 ? Qh : Kh) + (bh * SEQ + s) * DIM_HEAD + d;
            P[0]  = f2b(v0);
            P[32] = f2b(v1);
            P[64] = f2b(v2);
            P[96] = f2b(v3);
        }
    }
}

// ---------------------------------------------------------------------------
// Kernel 2: MFMA flash attention v4.
// Block = 32 queries, 4 waves each own 1024 keys (grid 2048 -> 8 blocks/CU).
// Wave = 2 Q-frags sharing K/V loads; register prefetch (always s0+32, no
// wrap branch — overshoot lands in adjacent ws regions, discarded).
// Softmax denominator via ones-MFMA: lacc = mfma(ones, P^T, lacc) gives the
// exact per-query column sums on the idle MFMA pipe (no VALU adds/shuffles).
// Register-only P transpose via permuted K rows pi(m)=8*(m>>2)+(m&3).
// ---------------------------------------------------------------------------
__global__ __launch_bounds__(256) void attn_mfma_kernel(
    const unsigned short* __restrict__ Qh, const unsigned short* __restrict__ Kh,
    const unsigned short* __restrict__ Vt, const float* __restrict__ T2,
    float* __restrict__ O)
{
    __shared__ float part[4][64][20];            // o0A,o1A,o0B,o1B,lA,lB

    const int lane = threadIdx.x & 63;
    const int wid  = threadIdx.x >> 6;
    const int c    = lane & 15;
    const int quad = lane >> 4;

    const int gw = blockIdx.x;                   // 0..2047
    const int q0 = (gw & 127) * 32;              // 32 queries per block
    const int h  = (gw >> 7) & (NUM_HEADS - 1);
    const int b  = gw >> 10;
    const size_t bh = (size_t)(b * NUM_HEADS + h);

    const float k2 = SCALE * LOG2E;
    const int perm = ((c & 12) << 1) | (c & 3);  // pi(c)

    const short8 qfA = *(const short8*)(Qh + (bh * SEQ + q0 + c)      * DIM_HEAD + quad * 8);
    const short8 qfB = *(const short8*)(Qh + (bh * SEQ + q0 + 16 + c) * DIM_HEAD + quad * 8);

    union { unsigned int u[4]; short8 s; } ones;
    ones.u[0] = ones.u[1] = ones.u[2] = ones.u[3] = 0x3F803F80u;  // bf16 1.0 x2

    const unsigned short* Kb = Kh + bh * SEQ * DIM_HEAD;
    const unsigned short* Vb = Vt + bh * DIM_HEAD * SEQ;
    const float* Tb = T2 + (size_t)b * SEQ;

    f32x4 o0A = {0.f,0.f,0.f,0.f}, o1A = {0.f,0.f,0.f,0.f};
    f32x4 o0B = {0.f,0.f,0.f,0.f}, o1B = {0.f,0.f,0.f,0.f};
    f32x4 lacc0 = {0.f,0.f,0.f,0.f}, lacc1 = {0.f,0.f,0.f,0.f};

    const int sbeg = wid * (SEQ / 4);
    const int send = sbeg + SEQ / 4;

    // pointer-bump bases for this wave
    const unsigned short* kp0 = Kb + (size_t)(sbeg + perm)     * DIM_HEAD + quad * 8;
    const unsigned short* kp1 = Kb + (size_t)(sbeg + perm + 4) * DIM_HEAD + quad * 8;
    const unsigned short* vp0 = Vb + (size_t)c        * SEQ + sbeg + quad * 8;
    const unsigned short* vp1 = Vb + (size_t)(16 + c) * SEQ + sbeg + quad * 8;
    const float* tp = Tb + sbeg + quad * 8;

    short8 kf0 = *(const short8*)kp0;
    short8 kf1 = *(const short8*)kp1;
    short8 vf0 = *(const short8*)vp0;
    short8 vf1 = *(const short8*)vp1;
    float4 t0 = *(const float4*)tp;
    float4 t1 = *(const float4*)(tp + 4);

    const f32x4 z = {0.f, 0.f, 0.f, 0.f};

    #pragma unroll 2
    for (int s0 = sbeg; s0 < send; s0 += 32) {
        // ---- prefetch next chunk (constant-offset loads; last is discarded)
        kp0 += 32 * DIM_HEAD; kp1 += 32 * DIM_HEAD;
        vp0 += 32; vp1 += 32; tp += 32;
        const short8 nk0 = *(const short8*)kp0;
        const short8 nk1 = *(const short8*)kp1;
        const short8 nv0 = *(const short8*)vp0;
        const short8 nv1 = *(const short8*)vp1;
        const float4 nt0 = *(const float4*)tp;
        const float4 nt1 = *(const float4*)(tp + 4);

        // ---- scores for both q-frags (K rows shared)
        const f32x4 s0A = __builtin_amdgcn_mfma_f32_16x16x32_bf16(kf0, qfA, z, 0, 0, 0);
        const f32x4 s1A = __builtin_amdgcn_mfma_f32_16x16x32_bf16(kf1, qfA, z, 0, 0, 0);
        const f32x4 s0B = __builtin_amdgcn_mfma_f32_16x16x32_bf16(kf0, qfB, z, 0, 0, 0);
        const f32x4 s1B = __builtin_amdgcn_mfma_f32_16x16x32_bf16(kf1, qfB, z, 0, 0, 0);

        // ---- p = exp2(score*k2 + mask), keys s0+8*quad+{0..7}
        float pA[8], pB[8];
        pA[0] = exp2f(fmaf(s0A[0], k2, t0.x));
        pA[1] = exp2f(fmaf(s0A[1], k2, t0.y));
        pA[2] = exp2f(fmaf(s0A[2], k2, t0.z));
        pA[3] = exp2f(fmaf(s0A[3], k2, t0.w));
        pA[4] = exp2f(fmaf(s1A[0], k2, t1.x));
        pA[5] = exp2f(fmaf(s1A[1], k2, t1.y));
        pA[6] = exp2f(fmaf(s1A[2], k2, t1.z));
        pA[7] = exp2f(fmaf(s1A[3], k2, t1.w));
        pB[0] = exp2f(fmaf(s0B[0], k2, t0.x));
        pB[1] = exp2f(fmaf(s0B[1], k2, t0.y));
        pB[2] = exp2f(fmaf(s0B[2], k2, t0.z));
        pB[3] = exp2f(fmaf(s0B[3], k2, t0.w));
        pB[4] = exp2f(fmaf(s1B[0], k2, t1.x));
        pB[5] = exp2f(fmaf(s1B[1], k2, t1.y));
        pB[6] = exp2f(fmaf(s1B[2], k2, t1.z));
        pB[7] = exp2f(fmaf(s1B[3], k2, t1.w));

        // ---- PV B-fragments in registers
        union { unsigned int u[4]; short8 s; } pfA, pfB;
        pfA.u[0] = pk_bf16(pA[0], pA[1]);
        pfA.u[1] = pk_bf16(pA[2], pA[3]);
        pfA.u[2] = pk_bf16(pA[4], pA[5]);
        pfA.u[3] = pk_bf16(pA[6], pA[7]);
        pfB.u[0] = pk_bf16(pB[0], pB[1]);
        pfB.u[1] = pk_bf16(pB[2], pB[3]);
        pfB.u[2] = pk_bf16(pB[4], pB[5]);
        pfB.u[3] = pk_bf16(pB[6], pB[7]);

        // ---- denominators on the MFMA pipe: column sums of P^T
        lacc0 = __builtin_amdgcn_mfma_f32_16x16x32_bf16(ones.s, pfA.s, lacc0, 0, 0, 0);
        lacc1 = __builtin_amdgcn_mfma_f32_16x16x32_bf16(ones.s, pfB.s, lacc1, 0, 0, 0);

        // ---- O^T += V^T x P^T (V rows shared by both q-frags)
        o0A = __builtin_amdgcn_mfma_f32_16x16x32_bf16(vf0, pfA.s, o0A, 0, 0, 0);
        o1A = __builtin_amdgcn_mfma_f32_16x16x32_bf16(vf1, pfA.s, o1A, 0, 0, 0);
        o0B = __builtin_amdgcn_mfma_f32_16x16x32_bf16(vf0, pfB.s, o0B, 0, 0, 0);
        o1B = __builtin_amdgcn_mfma_f32_16x16x32_bf16(vf1, pfB.s, o1B, 0, 0, 0);

        kf0 = nk0; kf1 = nk1; vf0 = nv0; vf1 = nv1; t0 = nt0; t1 = nt1;
    }

    // ---- per-wave partials (l already fully reduced by the ones-MFMA)
    *(f32x4*)&part[wid][lane][0]  = o0A;
    *(f32x4*)&part[wid][lane][4]  = o1A;
    *(f32x4*)&part[wid][lane][8]  = o0B;
    *(f32x4*)&part[wid][lane][12] = o1B;
    part[wid][lane][16] = lacc0[0];
    part[wid][lane][17] = lacc1[0];
    __syncthreads();

    if (wid == 0) {
        f32x4 a0A = o0A, a1A = o1A, a0B = o0B, a1B = o1B;
        float LA = lacc0[0], LB = lacc1[0];
        #pragma unroll
        for (int w = 1; w < 4; w++) {
            const f32x4 u0A = *(const f32x4*)&part[w][lane][0];
            const f32x4 u1A = *(const f32x4*)&part[w][lane][4];
            const f32x4 u0B = *(const f32x4*)&part[w][lane][8];
            const f32x4 u1B = *(const f32x4*)&part[w][lane][12];
            #pragma unroll
            for (int i = 0; i < 4; i++) {
                a0A[i] += u0A[i]; a1A[i] += u1A[i];
                a0B[i] += u0B[i]; a1B[i] += u1B[i];
            }
            LA += part[w][lane][16];
            LB += part[w][lane][17];
        }
        const float invA = 1.0f / LA;
        const float invB = 1.0f / LB;
        float* opA = O + ((size_t)(b * SEQ) + q0 + c) * D_MODEL + h * DIM_HEAD + quad * 4;
        *(float4*)opA        = make_float4(a0A[0]*invA, a0A[1]*invA, a0A[2]*invA, a0A[3]*invA);
        *(float4*)(opA + 16) = make_float4(a1A[0]*invA, a1A[1]*invA, a1A[2]*invA, a1A[3]*invA);
        float* opB = opA + 16 * D_MODEL;
        *(float4*)opB        = make_float4(a0B[0]*invB, a0B[1]*invB, a0B[2]*invB, a0B[3]*invB);
        *(float4*)(opB + 16) = make_float4(a1B[0]*invB, a1B[1]*invB, a1B[2]*invB, a1B[3]*invB);
    }
}

// ---------------------------------------------------------------------------
// Kernel 3: residual add + LayerNorm IN PLACE on d_out (fp32 -> fp32).
// ---------------------------------------------------------------------------
__global__ __launch_bounds__(256) void ln_kernel(
    float* AO,                     // aliased read A / write out — no restrict
    const float* __restrict__ x,
    const float* __restrict__ gamma, const float* __restrict__ beta)
{
    const int lane = threadIdx.x & 63;
    const int wid  = threadIdx.x >> 6;
    const size_t row = (size_t)blockIdx.x * 4 + wid;

    const float4 a  = ((const float4*)(AO + row * D_MODEL))[lane];
    const float4 xv = ((const float4*)(x + row * D_MODEL))[lane];
    float hv[4];
    hv[0] = a.x + xv.x;
    hv[1] = a.y + xv.y;
    hv[2] = a.z + xv.z;
    hv[3] = a.w + xv.w;

    float s = hv[0] + hv[1] + hv[2] + hv[3];
    #pragma unroll
    for (int off = 32; off > 0; off >>= 1) s += __shfl_xor(s, off, 64);
    const float mu = s * (1.0f / D_MODEL);

    float d0 = hv[0]-mu, d1 = hv[1]-mu, d2 = hv[2]-mu, d3 = hv[3]-mu;
    float ss = d0*d0 + d1*d1 + d2*d2 + d3*d3;
    #pragma unroll
    for (int off = 32; off > 0; off >>= 1) ss += __shfl_xor(ss, off, 64);
    const float rs = rsqrtf(ss * (1.0f / D_MODEL) + LN_EPS);

    const float4 g  = ((const float4*)gamma)[lane];
    const float4 bb = ((const float4*)beta)[lane];
    float4 y;
    y.x = g.x * d0 * rs + bb.x;
    y.y = g.y * d1 * rs + bb.y;
    y.z = g.z * d2 * rs + bb.z;
    y.w = g.w * d3 * rs + bb.w;
    ((float4*)(AO + row * D_MODEL))[lane] = y;
}

// ---------------------------------------------------------------------------
extern "C" void kernel_launch(void* const* d_in, const int* in_sizes, int n_in,
                              void* d_out, int out_size, void* d_ws, size_t ws_size,
                              hipStream_t stream)
{
    const float* x     = (const float*)d_in[0];
    const float* pad   = (const float*)d_in[1];
    const float* Wq    = (const float*)d_in[2];
    const float* bq    = (const float*)d_in[3];
    const float* Wk    = (const float*)d_in[4];
    const float* bk    = (const float*)d_in[5];
    const float* Wv    = (const float*)d_in[6];
    const float* bv    = (const float*)d_in[7];
    const float* gamma = (const float*)d_in[8];
    const float* beta  = (const float*)d_in[9];

    const size_t elems = (size_t)NROWS * D_MODEL;       // 2M
    unsigned short* Qh = (unsigned short*)d_ws;          // 4 MB
    unsigned short* Kh = Qh + elems;                     // 4 MB
    unsigned short* Vt = Kh + elems;                     // 4 MB
    float* T2 = (float*)(Vt + elems);                    // 32 KB
    unsigned short* Wt = (unsigned short*)(T2 + NROWS);  // 768x256 bf16, 384 KB
    float* biasc = (float*)(Wt + 768 * 256);             // 3 KB
    float* AO = (float*)d_out;                           // attn out + final out

    prep_kernel<<<800, 256, 0, stream>>>(Wq, Wk, Wv, bq, bk, bv, pad,
                                         Wt, biasc, T2);
    qkv_mfma_kernel<<<(NROWS / 64) * 8, 256, 0, stream>>>(x, Wt, biasc,
                                                          Qh, Kh, Vt);
    attn_mfma_kernel<<<BATCH * NUM_HEADS * (SEQ / 32), 256, 0, stream>>>(
        Qh, Kh, Vt, T2, AO);
    ln_kernel<<<NROWS / 4, 256, 0, stream>>>(AO, x, gamma, beta);
}

// Round 12
// 217.813 us; speedup vs baseline: 1.5799x; 1.0287x over previous
//
#include <hip/hip_runtime.h>
#include <hip/hip_bf16.h>

#define D_MODEL 256
#define NUM_HEADS 8
#define DIM_HEAD 32
#define SEQ 4096
#define BATCH 2
#define NROWS (BATCH * SEQ)              // 8192
#define LN_EPS 1e-6f
#define MASK_BIAS -1.0e9f
#define SCALE 0.17677669529663687f      // 1/sqrt(32)
#define LOG2E 1.4426950408889634f

typedef __attribute__((ext_vector_type(8))) short short8;   // 8 bf16 (4 VGPRs)
typedef __attribute__((ext_vector_type(4))) float f32x4;    // MFMA C/D

// fp32 -> bf16 bits (RNE)
static __device__ __forceinline__ unsigned short f2b(float f) {
    union { __hip_bfloat16 b; unsigned short u; } cv;
    cv.b = __float2bfloat16(f);
    return cv.u;
}
// packed fp32 pair -> bf16x2 (RNE), lo in low 16 bits
static __device__ __forceinline__ unsigned int pk_bf16(float lo, float hi) {
    union { __hip_bfloat162 v; unsigned int u; } cv;
    cv.v = __float22bfloat162_rn(make_float2(lo, hi));
    return cv.u;
}
// raw v_exp_f32: 1 instruction, full HW range (no libm fixup sequence)
static __device__ __forceinline__ float exp2_raw(float x) {
#if __has_builtin(__builtin_amdgcn_exp2f)
    return __builtin_amdgcn_exp2f(x);
#else
    float r;
    asm volatile("v_exp_f32 %0, %1" : "=v"(r) : "v"(x));
    return r;
#endif
}

// ---------------------------------------------------------------------------
// Kernel 0: prep. Blocks 0..767: Wt[n_cat][k] = W_w[k][n] (bf16) + bias.
// Block = one W row (coalesced reads, scattered fire-and-forget writes).
// Blocks 768..799: T2 = pad * (-1e9*scale*log2e).
// ---------------------------------------------------------------------------
__global__ __launch_bounds__(256) void prep_kernel(
    const float* __restrict__ Wq, const float* __restrict__ Wk,
    const float* __restrict__ Wv,
    const float* __restrict__ bq, const float* __restrict__ bk,
    const float* __restrict__ bv,
    const float* __restrict__ pad,
    unsigned short* __restrict__ Wt, float* __restrict__ biasc,
    float* __restrict__ T2)
{
    const int blk = blockIdx.x;
    const int t = threadIdx.x;
    if (blk < 768) {
        const int w = blk >> 8;          // 0=Q 1=K 2=V
        const int k = blk & 255;         // input row (contraction index)
        const float* W = (w == 0) ? Wq : (w == 1) ? Wk : Wv;
        Wt[(size_t)(w * 256 + t) * 256 + k] = f2b(W[(size_t)k * 256 + t]);
        if (k == 0) {
            const float* bb = (w == 0) ? bq : (w == 1) ? bk : bv;
            biasc[w * 256 + t] = bb[t];
        }
    } else {
        const int i = (blk - 768) * 256 + t;
        T2[i] = pad[i] * (MASK_BIAS * SCALE * LOG2E);
    }
}

// ---------------------------------------------------------------------------
// Kernel 1: QKV projection as bf16 MFMA GEMM. C = x[8192,256] @ Wt^T[256,768].
// Block = 4 waves = 64 rows x 96 cols; wave = 16 rows x 6 col-tiles.
// ---------------------------------------------------------------------------
__global__ __launch_bounds__(256) void qkv_mfma_kernel(
    const float* __restrict__ x, const unsigned short* __restrict__ Wt,
    const float* __restrict__ biasc,
    unsigned short* __restrict__ Qh, unsigned short* __restrict__ Kh,
    unsigned short* __restrict__ Vt)
{
    const int lane = threadIdx.x & 63;
    const int wid  = threadIdx.x >> 6;
    const int c    = lane & 15;
    const int quad = lane >> 4;

    const int r0 = (blockIdx.x >> 3) * 64 + wid * 16;   // wave row base
    const int n0 = (blockIdx.x & 7) * 96;               // wave col base

    f32x4 acc[6];
    float bias[6];
    #pragma unroll
    for (int t = 0; t < 6; t++) {
        acc[t] = (f32x4){0.f, 0.f, 0.f, 0.f};
        bias[t] = biasc[n0 + 16 * t + c];
    }

    const float* xp0 = x + (size_t)(r0 + c) * D_MODEL + quad * 8;
    const unsigned short* wp0 = Wt + (size_t)(n0 + c) * 256 + quad * 8;

    for (int k0 = 0; k0 < 256; k0 += 32) {
        const float4 a0 = *(const float4*)(xp0 + k0);
        const float4 a1 = *(const float4*)(xp0 + k0 + 4);
        union { unsigned int u[4]; short8 s; } af;
        af.u[0] = pk_bf16(a0.x, a0.y);
        af.u[1] = pk_bf16(a0.z, a0.w);
        af.u[2] = pk_bf16(a1.x, a1.y);
        af.u[3] = pk_bf16(a1.z, a1.w);
        #pragma unroll
        for (int t = 0; t < 6; t++) {
            const short8 bf = *(const short8*)(wp0 + (size_t)(16 * t) * 256 + k0);
            acc[t] = __builtin_amdgcn_mfma_f32_16x16x32_bf16(af.s, bf, acc[t], 0, 0, 0);
        }
    }

    #pragma unroll
    for (int t = 0; t < 6; t++) {
        const int col = n0 + 16 * t;          // tile col base (multiple of 16)
        const int mm  = col >> 8;             // 0=Q 1=K 2=V (uniform per tile)
        const int dim = (col & 255) + c;
        const int h = dim >> 5, d = dim & 31;
        const int row = r0 + quad * 4;        // rows row..row+3 (same batch)
        const int bb = row >> 12;
        const int s  = row & (SEQ - 1);
        const size_t bh = (size_t)(bb * NUM_HEADS + h);
        const float v0 = acc[t][0] + bias[t];
        const float v1 = acc[t][1] + bias[t];
        const float v2 = acc[t][2] + bias[t];
        const float v3 = acc[t][3] + bias[t];
        if (mm == 2) {
            uint2 pk = make_uint2(pk_bf16(v0, v1), pk_bf16(v2, v3));
            *(uint2*)(Vt + (bh * DIM_HEAD + d) * SEQ + s) = pk;
        } else {
            unsigned short* P = (mm == 0 ? Qh : Kh) + (bh * SEQ + s) * DIM_HEAD + d;
            P[0]  = f2b(v0);
            P[32] = f2b(v1);
            P[64] = f2b(v2);
            P[96] = f2b(v3);
        }
    }
}

// ---------------------------------------------------------------------------
// Kernel 2: MFMA flash attention v5.
// Block = 32 queries; 4 waves each own 1024 keys (grid 2048).
// Ping-pong register double-buffer (two full load-register sets, base
// pointers bumped once per 64 keys, constant-offset loads) — no rotation
// movs. Raw v_exp_f32 for softmax. Denominator via ones-MFMA. Register-only
// P transpose via permuted K rows pi(m)=8*(m>>2)+(m&3). Prefetch overshoots
// past the key range by design (lands in adjacent ws regions, discarded).
// ---------------------------------------------------------------------------
__global__ __launch_bounds__(256) void attn_mfma_kernel(
    const unsigned short* __restrict__ Qh, const unsigned short* __restrict__ Kh,
    const unsigned short* __restrict__ Vt, const float* __restrict__ T2,
    float* __restrict__ O)
{
    __shared__ float part[3][64][18];            // waves 1..3 spill partials

    const int lane = threadIdx.x & 63;
    const int wid  = threadIdx.x >> 6;
    const int c    = lane & 15;
    const int quad = lane >> 4;

    const int gw = blockIdx.x;                   // 0..2047
    const int q0 = (gw & 127) * 32;              // 32 queries per block
    const int h  = (gw >> 7) & (NUM_HEADS - 1);
    const int b  = gw >> 10;
    const size_t bh = (size_t)(b * NUM_HEADS + h);

    const float k2 = SCALE * LOG2E;
    const int perm = ((c & 12) << 1) | (c & 3);  // pi(c)

    const short8 qfA = *(const short8*)(Qh + (bh * SEQ + q0 + c)      * DIM_HEAD + quad * 8);
    const short8 qfB = *(const short8*)(Qh + (bh * SEQ + q0 + 16 + c) * DIM_HEAD + quad * 8);

    union { unsigned int u[4]; short8 s; } ones;
    ones.u[0] = ones.u[1] = ones.u[2] = ones.u[3] = 0x3F803F80u;  // bf16 1.0 x2

    f32x4 o0A = {0.f,0.f,0.f,0.f}, o1A = {0.f,0.f,0.f,0.f};
    f32x4 o0B = {0.f,0.f,0.f,0.f}, o1B = {0.f,0.f,0.f,0.f};
    f32x4 lacc0 = {0.f,0.f,0.f,0.f}, lacc1 = {0.f,0.f,0.f,0.f};
    const f32x4 z = {0.f, 0.f, 0.f, 0.f};

    // one 32-key chunk: 4 score MFMAs, 16 raw exp2, 8 packs, 2 l-MFMAs, 4 o-MFMAs
    auto step = [&](const short8& K0, const short8& K1,
                    const short8& V0, const short8& V1,
                    const float4& T0, const float4& T1) {
        const f32x4 s0A = __builtin_amdgcn_mfma_f32_16x16x32_bf16(K0, qfA, z, 0, 0, 0);
        const f32x4 s1A = __builtin_amdgcn_mfma_f32_16x16x32_bf16(K1, qfA, z, 0, 0, 0);
        const f32x4 s0B = __builtin_amdgcn_mfma_f32_16x16x32_bf16(K0, qfB, z, 0, 0, 0);
        const f32x4 s1B = __builtin_amdgcn_mfma_f32_16x16x32_bf16(K1, qfB, z, 0, 0, 0);

        float pA[8], pB[8];
        pA[0] = exp2_raw(fmaf(s0A[0], k2, T0.x));
        pA[1] = exp2_raw(fmaf(s0A[1], k2, T0.y));
        pA[2] = exp2_raw(fmaf(s0A[2], k2, T0.z));
        pA[3] = exp2_raw(fmaf(s0A[3], k2, T0.w));
        pA[4] = exp2_raw(fmaf(s1A[0], k2, T1.x));
        pA[5] = exp2_raw(fmaf(s1A[1], k2, T1.y));
        pA[6] = exp2_raw(fmaf(s1A[2], k2, T1.z));
        pA[7] = exp2_raw(fmaf(s1A[3], k2, T1.w));
        pB[0] = exp2_raw(fmaf(s0B[0], k2, T0.x));
        pB[1] = exp2_raw(fmaf(s0B[1], k2, T0.y));
        pB[2] = exp2_raw(fmaf(s0B[2], k2, T0.z));
        pB[3] = exp2_raw(fmaf(s0B[3], k2, T0.w));
        pB[4] = exp2_raw(fmaf(s1B[0], k2, T1.x));
        pB[5] = exp2_raw(fmaf(s1B[1], k2, T1.y));
        pB[6] = exp2_raw(fmaf(s1B[2], k2, T1.z));
        pB[7] = exp2_raw(fmaf(s1B[3], k2, T1.w));

        union { unsigned int u[4]; short8 s; } pfA, pfB;
        pfA.u[0] = pk_bf16(pA[0], pA[1]);
        pfA.u[1] = pk_bf16(pA[2], pA[3]);
        pfA.u[2] = pk_bf16(pA[4], pA[5]);
        pfA.u[3] = pk_bf16(pA[6], pA[7]);
        pfB.u[0] = pk_bf16(pB[0], pB[1]);
        pfB.u[1] = pk_bf16(pB[2], pB[3]);
        pfB.u[2] = pk_bf16(pB[4], pB[5]);
        pfB.u[3] = pk_bf16(pB[6], pB[7]);

        lacc0 = __builtin_amdgcn_mfma_f32_16x16x32_bf16(ones.s, pfA.s, lacc0, 0, 0, 0);
        lacc1 = __builtin_amdgcn_mfma_f32_16x16x32_bf16(ones.s, pfB.s, lacc1, 0, 0, 0);

        o0A = __builtin_amdgcn_mfma_f32_16x16x32_bf16(V0, pfA.s, o0A, 0, 0, 0);
        o1A = __builtin_amdgcn_mfma_f32_16x16x32_bf16(V1, pfA.s, o1A, 0, 0, 0);
        o0B = __builtin_amdgcn_mfma_f32_16x16x32_bf16(V0, pfB.s, o0B, 0, 0, 0);
        o1B = __builtin_amdgcn_mfma_f32_16x16x32_bf16(V1, pfB.s, o1B, 0, 0, 0);
    };

    const int sbeg = wid * (SEQ / 4);
    const unsigned short* kp0 = Kh + bh * SEQ * DIM_HEAD
                              + (size_t)(sbeg + perm) * DIM_HEAD + quad * 8;
    const unsigned short* kp1 = kp0 + 4 * DIM_HEAD;
    const unsigned short* vp0 = Vt + bh * DIM_HEAD * SEQ
                              + (size_t)c * SEQ + sbeg + quad * 8;
    const unsigned short* vp1 = vp0 + 16 * SEQ;
    const float* tp = T2 + (size_t)b * SEQ + sbeg + quad * 8;

    // ping-pong register sets
    short8 k0a = *(const short8*)kp0;
    short8 k1a = *(const short8*)kp1;
    short8 v0a = *(const short8*)vp0;
    short8 v1a = *(const short8*)vp1;
    float4 t0a = *(const float4*)tp;
    float4 t1a = *(const float4*)(tp + 4);

    #define KOFF (32 * DIM_HEAD)
    for (int it = 0; it < (SEQ / 4) / 64; ++it) {
        // prefetch odd chunk into set b (base + 32 keys)
        const short8 k0b = *(const short8*)(kp0 + KOFF);
        const short8 k1b = *(const short8*)(kp1 + KOFF);
        const short8 v0b = *(const short8*)(vp0 + 32);
        const short8 v1b = *(const short8*)(vp1 + 32);
        const float4 t0b = *(const float4*)(tp + 32);
        const float4 t1b = *(const float4*)(tp + 36);

        step(k0a, k1a, v0a, v1a, t0a, t1a);

        // advance base by 64 keys; prefetch next even chunk into set a
        kp0 += 2 * KOFF; kp1 += 2 * KOFF; vp0 += 64; vp1 += 64; tp += 64;
        k0a = *(const short8*)kp0;
        k1a = *(const short8*)kp1;
        v0a = *(const short8*)vp0;
        v1a = *(const short8*)vp1;
        t0a = *(const float4*)tp;
        t1a = *(const float4*)(tp + 4);

        step(k0b, k1b, v0b, v1b, t0b, t1b);
    }
    #undef KOFF

    // ---- waves 1..3 spill partials; wave 0 combines (l fully reduced by ones-MFMA)
    if (wid != 0) {
        *(f32x4*)&part[wid - 1][lane][0]  = o0A;
        *(f32x4*)&part[wid - 1][lane][4]  = o1A;
        *(f32x4*)&part[wid - 1][lane][8]  = o0B;
        *(f32x4*)&part[wid - 1][lane][12] = o1B;
        part[wid - 1][lane][16] = lacc0[0];
        part[wid - 1][lane][17] = lacc1[0];
    }
    __syncthreads();

    if (wid == 0) {
        float LA = lacc0[0], LB = lacc1[0];
        #pragma unroll
        for (int w = 0; w < 3; w++) {
            const f32x4 u0A = *(const f32x4*)&part[w][lane][0];
            const f32x4 u1A = *(const f32x4*)&part[w][lane][4];
            const f32x4 u0B = *(const f32x4*)&part[w][lane][8];
            const f32x4 u1B = *(const f32x4*)&part[w][lane][12];
            #pragma unroll
            for (int i = 0; i < 4; i++) {
                o0A[i] += u0A[i]; o1A[i] += u1A[i];
                o0B[i] += u0B[i]; o1B[i] += u1B[i];
            }
            LA += part[w][lane][16];
            LB += part[w][lane][17];
        }
        const float invA = 1.0f / LA;
        const float invB = 1.0f / LB;
        float* opA = O + ((size_t)(b * SEQ) + q0 + c) * D_MODEL + h * DIM_HEAD + quad * 4;
        *(float4*)opA        = make_float4(o0A[0]*invA, o0A[1]*invA, o0A[2]*invA, o0A[3]*invA);
        *(float4*)(opA + 16) = make_float4(o1A[0]*invA, o1A[1]*invA, o1A[2]*invA, o1A[3]*invA);
        float* opB = opA + 16 * D_MODEL;
        *(float4*)opB        = make_float4(o0B[0]*invB, o0B[1]*invB, o0B[2]*invB, o0B[3]*invB);
        *(float4*)(opB + 16) = make_float4(o1B[0]*invB, o1B[1]*invB, o1B[2]*invB, o1B[3]*invB);
    }
}

// ---------------------------------------------------------------------------
// Kernel 3: residual add + LayerNorm IN PLACE on d_out (fp32 -> fp32).
// ---------------------------------------------------------------------------
__global__ __launch_bounds__(256) void ln_kernel(
    float* AO,                     // aliased read A / write out — no restrict
    const float* __restrict__ x,
    const float* __restrict__ gamma, const float* __restrict__ beta)
{
    const int lane = threadIdx.x & 63;
    const int wid  = threadIdx.x >> 6;
    const size_t row = (size_t)blockIdx.x * 4 + wid;

    const float4 a  = ((const float4*)(AO + row * D_MODEL))[lane];
    const float4 xv = ((const float4*)(x + row * D_MODEL))[lane];
    float hv[4];
    hv[0] = a.x + xv.x;
    hv[1] = a.y + xv.y;
    hv[2] = a.z + xv.z;
    hv[3] = a.w + xv.w;

    float s = hv[0] + hv[1] + hv[2] + hv[3];
    #pragma unroll
    for (int off = 32; off > 0; off >>= 1) s += __shfl_xor(s, off, 64);
    const float mu = s * (1.0f / D_MODEL);

    float d0 = hv[0]-mu, d1 = hv[1]-mu, d2 = hv[2]-mu, d3 = hv[3]-mu;
    float ss = d0*d0 + d1*d1 + d2*d2 + d3*d3;
    #pragma unroll
    for (int off = 32; off > 0; off >>= 1) ss += __shfl_xor(ss, off, 64);
    const float rs = rsqrtf(ss * (1.0f / D_MODEL) + LN_EPS);

    const float4 g  = ((const float4*)gamma)[lane];
    const float4 bb = ((const float4*)beta)[lane];
    float4 y;
    y.x = g.x * d0 * rs + bb.x;
    y.y = g.y * d1 * rs + bb.y;
    y.z = g.z * d2 * rs + bb.z;
    y.w = g.w * d3 * rs + bb.w;
    ((float4*)(AO + row * D_MODEL))[lane] = y;
}

// ---------------------------------------------------------------------------
extern "C" void kernel_launch(void* const* d_in, const int* in_sizes, int n_in,
                              void* d_out, int out_size, void* d_ws, size_t ws_size,
                              hipStream_t stream)
{
    const float* x     = (const float*)d_in[0];
    const float* pad   = (const float*)d_in[1];
    const float* Wq    = (const float*)d_in[2];
    const float* bq    = (const float*)d_in[3];
    const float* Wk    = (const float*)d_in[4];
    const float* bk    = (const float*)d_in[5];
    const float* Wv    = (const float*)d_in[6];
    const float* bv    = (const float*)d_in[7];
    const float* gamma = (const float*)d_in[8];
    const float* beta  = (const float*)d_in[9];

    const size_t elems = (size_t)NROWS * D_MODEL;       // 2M
    unsigned short* Qh = (unsigned short*)d_ws;          // 4 MB
    unsigned short* Kh = Qh + elems;                     // 4 MB
    unsigned short* Vt = Kh + elems;                     // 4 MB
    float* T2 = (float*)(Vt + elems);                    // 32 KB
    unsigned short* Wt = (unsigned short*)(T2 + NROWS);  // 768x256 bf16, 384 KB
    float* biasc = (float*)(Wt + 768 * 256);             // 3 KB
    float* AO = (float*)d_out;                           // attn out + final out

    prep_kernel<<<800, 256, 0, stream>>>(Wq, Wk, Wv, bq, bk, bv, pad,
                                         Wt, biasc, T2);
    qkv_mfma_kernel<<<(NROWS / 64) * 8, 256, 0, stream>>>(x, Wt, biasc,
                                                          Qh, Kh, Vt);
    attn_mfma_kernel<<<BATCH * NUM_HEADS * (SEQ / 32), 256, 0, stream>>>(
        Qh, Kh, Vt, T2, AO);
    ln_kernel<<<NROWS / 4, 256, 0, stream>>>(AO, x, gamma, beta);
}

// Round 13
// 188.818 us; speedup vs baseline: 1.8225x; 1.1536x over previous
//
#include <hip/hip_runtime.h>
#include <hip/hip_bf16.h>

#define D_MODEL 256
#define NUM_HEADS 8
#define DIM_HEAD 32
#define SEQ 4096
#define BATCH 2
#define NROWS (BATCH * SEQ)              // 8192
#define LN_EPS 1e-6f
#define MASK_BIAS -1.0e9f
#define SCALE 0.17677669529663687f      // 1/sqrt(32)
#define LOG2E 1.4426950408889634f

typedef __attribute__((ext_vector_type(8))) short short8;   // 8 bf16 (4 VGPRs)
typedef __attribute__((ext_vector_type(4))) float f32x4;    // MFMA C/D

// fp32 -> bf16 bits (RNE)
static __device__ __forceinline__ unsigned short f2b(float f) {
    union { __hip_bfloat16 b; unsigned short u; } cv;
    cv.b = __float2bfloat16(f);
    return cv.u;
}
// packed fp32 pair -> bf16x2 (RNE), lo in low 16 bits
static __device__ __forceinline__ unsigned int pk_bf16(float lo, float hi) {
    union { __hip_bfloat162 v; unsigned int u; } cv;
    cv.v = __float22bfloat162_rn(make_float2(lo, hi));
    return cv.u;
}
// raw v_exp_f32: 1 instruction (no libm fixup) — confirmed win in R12
static __device__ __forceinline__ float exp2_raw(float x) {
#if __has_builtin(__builtin_amdgcn_exp2f)
    return __builtin_amdgcn_exp2f(x);
#else
    float r;
    asm volatile("v_exp_f32 %0, %1" : "=v"(r) : "v"(x));
    return r;
#endif
}
// async global->LDS, 16B per lane; LDS dest = uniform base + lane*16
static __device__ __forceinline__ void load_lds16(const void* g, void* l) {
    __builtin_amdgcn_global_load_lds(
        (const __attribute__((address_space(1))) unsigned int*)g,
        (__attribute__((address_space(3))) unsigned int*)l, 16, 0, 0);
}

// ---------------------------------------------------------------------------
// Kernel 0: prep. Blocks 0..767: Wt[n_cat][k] = W_w[k][n] (bf16) + bias.
// Blocks 768..799: T2 = pad * (-1e9*scale*log2e).
// ---------------------------------------------------------------------------
__global__ __launch_bounds__(256) void prep_kernel(
    const float* __restrict__ Wq, const float* __restrict__ Wk,
    const float* __restrict__ Wv,
    const float* __restrict__ bq, const float* __restrict__ bk,
    const float* __restrict__ bv,
    const float* __restrict__ pad,
    unsigned short* __restrict__ Wt, float* __restrict__ biasc,
    float* __restrict__ T2)
{
    const int blk = blockIdx.x;
    const int t = threadIdx.x;
    if (blk < 768) {
        const int w = blk >> 8;          // 0=Q 1=K 2=V
        const int k = blk & 255;         // input row (contraction index)
        const float* W = (w == 0) ? Wq : (w == 1) ? Wk : Wv;
        Wt[(size_t)(w * 256 + t) * 256 + k] = f2b(W[(size_t)k * 256 + t]);
        if (k == 0) {
            const float* bb = (w == 0) ? bq : (w == 1) ? bk : bv;
            biasc[w * 256 + t] = bb[t];
        }
    } else {
        const int i = (blk - 768) * 256 + t;
        T2[i] = pad[i] * (MASK_BIAS * SCALE * LOG2E);
    }
}

// ---------------------------------------------------------------------------
// Kernel 1: QKV projection as bf16 MFMA GEMM (unchanged from R12).
// ---------------------------------------------------------------------------
__global__ __launch_bounds__(256) void qkv_mfma_kernel(
    const float* __restrict__ x, const unsigned short* __restrict__ Wt,
    const float* __restrict__ biasc,
    unsigned short* __restrict__ Qh, unsigned short* __restrict__ Kh,
    unsigned short* __restrict__ Vt)
{
    const int lane = threadIdx.x & 63;
    const int wid  = threadIdx.x >> 6;
    const int c    = lane & 15;
    const int quad = lane >> 4;

    const int r0 = (blockIdx.x >> 3) * 64 + wid * 16;   // wave row base
    const int n0 = (blockIdx.x & 7) * 96;               // wave col base

    f32x4 acc[6];
    float bias[6];
    #pragma unroll
    for (int t = 0; t < 6; t++) {
        acc[t] = (f32x4){0.f, 0.f, 0.f, 0.f};
        bias[t] = biasc[n0 + 16 * t + c];
    }

    const float* xp0 = x + (size_t)(r0 + c) * D_MODEL + quad * 8;
    const unsigned short* wp0 = Wt + (size_t)(n0 + c) * 256 + quad * 8;

    for (int k0 = 0; k0 < 256; k0 += 32) {
        const float4 a0 = *(const float4*)(xp0 + k0);
        const float4 a1 = *(const float4*)(xp0 + k0 + 4);
        union { unsigned int u[4]; short8 s; } af;
        af.u[0] = pk_bf16(a0.x, a0.y);
        af.u[1] = pk_bf16(a0.z, a0.w);
        af.u[2] = pk_bf16(a1.x, a1.y);
        af.u[3] = pk_bf16(a1.z, a1.w);
        #pragma unroll
        for (int t = 0; t < 6; t++) {
            const short8 bf = *(const short8*)(wp0 + (size_t)(16 * t) * 256 + k0);
            acc[t] = __builtin_amdgcn_mfma_f32_16x16x32_bf16(af.s, bf, acc[t], 0, 0, 0);
        }
    }

    #pragma unroll
    for (int t = 0; t < 6; t++) {
        const int col = n0 + 16 * t;          // tile col base (multiple of 16)
        const int mm  = col >> 8;             // 0=Q 1=K 2=V (uniform per tile)
        const int dim = (col & 255) + c;
        const int h = dim >> 5, d = dim & 31;
        const int row = r0 + quad * 4;        // rows row..row+3 (same batch)
        const int bb = row >> 12;
        const int s  = row & (SEQ - 1);
        const size_t bh = (size_t)(bb * NUM_HEADS + h);
        const float v0 = acc[t][0] + bias[t];
        const float v1 = acc[t][1] + bias[t];
        const float v2 = acc[t][2] + bias[t];
        const float v3 = acc[t][3] + bias[t];
        if (mm == 2) {
            uint2 pk = make_uint2(pk_bf16(v0, v1), pk_bf16(v2, v3));
            *(uint2*)(Vt + (bh * DIM_HEAD + d) * SEQ + s) = pk;
        } else {
            unsigned short* P = (mm == 0 ? Qh : Kh) + (bh * SEQ + s) * DIM_HEAD + d;
            P[0]  = f2b(v0);
            P[32] = f2b(v1);
            P[64] = f2b(v2);
            P[96] = f2b(v3);
        }
    }
}

// ---------------------------------------------------------------------------
// Kernel 2: MFMA flash attention v6 — cooperative async LDS staging.
// Block = 64 queries (4 waves x 16q), ALL waves share every 64-key chunk.
// Chunk staged via global_load_lds (K 4KB + V 4KB + T 256B) double-buffered;
// one __syncthreads per chunk (drains vmcnt). XOR swizzle folded into the
// staging *global* addresses (LDS placement is forced linear): K dim-group
// g^f(key), f=((key>>1)^(key>>3))&3; V key-group g^(dim&7) -> <=2-way bank
// aliasing on reads (free). Math identical to R12 (perm trick, ones-MFMA
// denominator, raw v_exp_f32). No key-split => no partial combine at all.
// ---------------------------------------------------------------------------
__global__ __launch_bounds__(256, 4) void attn_mfma_kernel(
    const unsigned short* __restrict__ Qh, const unsigned short* __restrict__ Kh,
    const unsigned short* __restrict__ Vt, const float* __restrict__ T2,
    float* __restrict__ O)
{
    __shared__ __align__(16) unsigned short ldsK[2][64 * 32];  // [key][dimgrp] 2x4KB
    __shared__ __align__(16) unsigned short ldsV[2][32 * 64];  // [dim][keygrp] 2x4KB
    __shared__ __align__(16) float          ldsT[2][64];       // 2x256B

    const int lane = threadIdx.x & 63;
    const int wid  = threadIdx.x >> 6;
    const int c    = lane & 15;
    const int quad = lane >> 4;

    const int gw = blockIdx.x;                   // 0..1023
    const int q0 = (gw & 63) * 64;               // 64 queries per block
    const int h  = (gw >> 6) & (NUM_HEADS - 1);
    const int b  = gw >> 9;
    const size_t bh = (size_t)(b * NUM_HEADS + h);

    const float k2 = SCALE * LOG2E;
    const int perm = ((c & 12) << 1) | (c & 3);  // pi(c)

    const unsigned short* Kb = Kh + bh * SEQ * DIM_HEAD;
    const unsigned short* Vb = Vt + bh * DIM_HEAD * SEQ;
    const float* Tb = T2 + (size_t)b * SEQ;

    // wave's 16 queries: q0 + wid*16 + c
    const int qrow = q0 + wid * 16;
    const short8 qf = *(const short8*)(Qh + (bh * SEQ + qrow + c) * DIM_HEAD + quad * 8);

    union { unsigned int u[4]; short8 s; } ones;
    ones.u[0] = ones.u[1] = ones.u[2] = ones.u[3] = 0x3F803F80u;  // bf16 1.0 x2

    // loop-invariant LDS read offsets (elements)
    const int f0 = ((perm >> 1) ^ (perm >> 3)) & 3;
    const int f1 = (((perm + 4) >> 1) ^ ((perm + 4) >> 3)) & 3;
    const int kA = perm * 32 + ((quad ^ f0) << 3);        // + sub*1024
    const int kB = (perm + 4) * 32 + ((quad ^ f1) << 3);
    const int g0 = quad ^ (c & 7);
    const int vA0 = c * 64 + (g0 << 3);
    const int vA1 = c * 64 + ((g0 ^ 4) << 3);
    const int vB0 = (16 + c) * 64 + (g0 << 3);
    const int vB1 = (16 + c) * 64 + ((g0 ^ 4) << 3);

    // staging lane constants
    const int skey = (lane >> 2);                // + j*16
    const int sgK  = lane & 3;
    const int sdim = lane >> 3;                  // + j*8
    const int sgV  = lane & 7;

    f32x4 o0 = {0.f,0.f,0.f,0.f}, o1 = {0.f,0.f,0.f,0.f};
    f32x4 lacc = {0.f,0.f,0.f,0.f};
    const f32x4 z = {0.f, 0.f, 0.f, 0.f};

    // stage chunk ch into buffer pb (wave-split: w0/w1 -> K, w2/w3 -> V(+T))
    auto stage = [&](int ch, int pb) {
        const int s0 = ch * 64;
        if (wid < 2) {
            #pragma unroll
            for (int jj = 0; jj < 2; jj++) {
                const int j = wid * 2 + jj;
                const int key = j * 16 + skey;
                const int f = ((key >> 1) ^ (key >> 3)) & 3;
                load_lds16(Kb + (size_t)(s0 + key) * 32 + ((sgK ^ f) << 3),
                           &ldsK[pb][j * 512]);
            }
        } else {
            #pragma unroll
            for (int jj = 0; jj < 2; jj++) {
                const int j = (wid - 2) * 2 + jj;
                const int dim = j * 8 + sdim;
                load_lds16(Vb + (size_t)dim * SEQ + s0 + ((sgV ^ (dim & 7)) << 3),
                           &ldsV[pb][j * 512]);
            }
            if (wid == 3 && lane < 16)
                load_lds16(Tb + s0 + lane * 4, &ldsT[pb][0]);
        }
    };

    // one 32-key sub-chunk from LDS buffer pb
    auto sub = [&](int pb, int s) {
        const short8 kf0 = *(const short8*)&ldsK[pb][s * 1024 + kA];
        const short8 kf1 = *(const short8*)&ldsK[pb][s * 1024 + kB];
        const short8 vf0 = *(const short8*)&ldsV[pb][s ? vA1 : vA0];
        const short8 vf1 = *(const short8*)&ldsV[pb][s ? vB1 : vB0];
        const float4 t0 = *(const float4*)&ldsT[pb][s * 32 + quad * 8];
        const float4 t1 = *(const float4*)&ldsT[pb][s * 32 + quad * 8 + 4];

        const f32x4 st0 = __builtin_amdgcn_mfma_f32_16x16x32_bf16(kf0, qf, z, 0, 0, 0);
        const f32x4 st1 = __builtin_amdgcn_mfma_f32_16x16x32_bf16(kf1, qf, z, 0, 0, 0);

        float p[8];
        p[0] = exp2_raw(fmaf(st0[0], k2, t0.x));
        p[1] = exp2_raw(fmaf(st0[1], k2, t0.y));
        p[2] = exp2_raw(fmaf(st0[2], k2, t0.z));
        p[3] = exp2_raw(fmaf(st0[3], k2, t0.w));
        p[4] = exp2_raw(fmaf(st1[0], k2, t1.x));
        p[5] = exp2_raw(fmaf(st1[1], k2, t1.y));
        p[6] = exp2_raw(fmaf(st1[2], k2, t1.z));
        p[7] = exp2_raw(fmaf(st1[3], k2, t1.w));

        union { unsigned int u[4]; short8 s8; } pf;
        pf.u[0] = pk_bf16(p[0], p[1]);
        pf.u[1] = pk_bf16(p[2], p[3]);
        pf.u[2] = pk_bf16(p[4], p[5]);
        pf.u[3] = pk_bf16(p[6], p[7]);

        lacc = __builtin_amdgcn_mfma_f32_16x16x32_bf16(ones.s, pf.s8, lacc, 0, 0, 0);
        o0   = __builtin_amdgcn_mfma_f32_16x16x32_bf16(vf0,   pf.s8, o0,   0, 0, 0);
        o1   = __builtin_amdgcn_mfma_f32_16x16x32_bf16(vf1,   pf.s8, o1,   0, 0, 0);
    };

    stage(0, 0);
    __syncthreads();
    for (int ch = 0; ch < SEQ / 64; ++ch) {
        const int pb = ch & 1;
        stage((ch + 1) & 63, pb ^ 1);    // async prefetch into other buffer
        sub(pb, 0);
        sub(pb, 1);
        __syncthreads();                 // drains vmcnt; fences both buffers
    }

    // normalize + store: every lane's lacc[0] = denominator of query col c
    const float inv = 1.0f / lacc[0];
    float* op = O + ((size_t)(b * SEQ) + qrow + c) * D_MODEL + h * DIM_HEAD + quad * 4;
    *(float4*)op        = make_float4(o0[0]*inv, o0[1]*inv, o0[2]*inv, o0[3]*inv);
    *(float4*)(op + 16) = make_float4(o1[0]*inv, o1[1]*inv, o1[2]*inv, o1[3]*inv);
}

// ---------------------------------------------------------------------------
// Kernel 3: residual add + LayerNorm IN PLACE on d_out (fp32 -> fp32).
// ---------------------------------------------------------------------------
__global__ __launch_bounds__(256) void ln_kernel(
    float* AO,                     // aliased read A / write out — no restrict
    const float* __restrict__ x,
    const float* __restrict__ gamma, const float* __restrict__ beta)
{
    const int lane = threadIdx.x & 63;
    const int wid  = threadIdx.x >> 6;
    const size_t row = (size_t)blockIdx.x * 4 + wid;

    const float4 a  = ((const float4*)(AO + row * D_MODEL))[lane];
    const float4 xv = ((const float4*)(x + row * D_MODEL))[lane];
    float hv[4];
    hv[0] = a.x + xv.x;
    hv[1] = a.y + xv.y;
    hv[2] = a.z + xv.z;
    hv[3] = a.w + xv.w;

    float s = hv[0] + hv[1] + hv[2] + hv[3];
    #pragma unroll
    for (int off = 32; off > 0; off >>= 1) s += __shfl_xor(s, off, 64);
    const float mu = s * (1.0f / D_MODEL);

    float d0 = hv[0]-mu, d1 = hv[1]-mu, d2 = hv[2]-mu, d3 = hv[3]-mu;
    float ss = d0*d0 + d1*d1 + d2*d2 + d3*d3;
    #pragma unroll
    for (int off = 32; off > 0; off >>= 1) ss += __shfl_xor(ss, off, 64);
    const float rs = rsqrtf(ss * (1.0f / D_MODEL) + LN_EPS);

    const float4 g  = ((const float4*)gamma)[lane];
    const float4 bb = ((const float4*)beta)[lane];
    float4 y;
    y.x = g.x * d0 * rs + bb.x;
    y.y = g.y * d1 * rs + bb.y;
    y.z = g.z * d2 * rs + bb.z;
    y.w = g.w * d3 * rs + bb.w;
    ((float4*)(AO + row * D_MODEL))[lane] = y;
}

// ---------------------------------------------------------------------------
extern "C" void kernel_launch(void* const* d_in, const int* in_sizes, int n_in,
                              void* d_out, int out_size, void* d_ws, size_t ws_size,
                              hipStream_t stream)
{
    const float* x     = (const float*)d_in[0];
    const float* pad   = (const float*)d_in[1];
    const float* Wq    = (const float*)d_in[2];
    const float* bq    = (const float*)d_in[3];
    const float* Wk    = (const float*)d_in[4];
    const float* bk    = (const float*)d_in[5];
    const float* Wv    = (const float*)d_in[6];
    const float* bv    = (const float*)d_in[7];
    const float* gamma = (const float*)d_in[8];
    const float* beta  = (const float*)d_in[9];

    const size_t elems = (size_t)NROWS * D_MODEL;       // 2M
    unsigned short* Qh = (unsigned short*)d_ws;          // 4 MB
    unsigned short* Kh = Qh + elems;                     // 4 MB
    unsigned short* Vt = Kh + elems;                     // 4 MB
    float* T2 = (float*)(Vt + elems);                    // 32 KB
    unsigned short* Wt = (unsigned short*)(T2 + NROWS);  // 768x256 bf16, 384 KB
    float* biasc = (float*)(Wt + 768 * 256);             // 3 KB
    float* AO = (float*)d_out;                           // attn out + final out

    prep_kernel<<<800, 256, 0, stream>>>(Wq, Wk, Wv, bq, bk, bv, pad,
                                         Wt, biasc, T2);
    qkv_mfma_kernel<<<(NROWS / 64) * 8, 256, 0, stream>>>(x, Wt, biasc,
                                                          Qh, Kh, Vt);
    attn_mfma_kernel<<<BATCH * NUM_HEADS * (SEQ / 64), 256, 0, stream>>>(
        Qh, Kh, Vt, T2, AO);
    ln_kernel<<<NROWS / 4, 256, 0, stream>>>(AO, x, gamma, beta);
}